// Round 12
// baseline (2075.691 us; speedup 1.0000x reference)
//
#include <hip/hip_runtime.h>
#include <hip/hip_bf16.h>

#define BB 64
#define EE 512
#define HH 1024
#define KK 1536
#define VV 50257
#define SS 512

#define NWG1 64    // G1 blocks: mi=bid&3 (16 rows), ni=bid>>2 (16 x 64-col tiles)
#define NWG2 32    // G2 blocks: mi=rb&3,  ni=rb>>2 (8 x 64-col tiles)
#define NWG (NWG1 + NWG2)
#define RINGM 64   // mid-ws fallback ring (round-11 proven kernel)
#define PADU 32    // unsigned per flag slot = 128 B line (mid path)

typedef __bf16 bf16x8 __attribute__((ext_vector_type(8)));
typedef float f32x4 __attribute__((ext_vector_type(4)));
typedef unsigned u32x4 __attribute__((ext_vector_type(4)));

__device__ __forceinline__ bf16x8 load_bf8(const __bf16* p) {
    return *reinterpret_cast<const bf16x8*>(p);
}

__device__ __forceinline__ bf16x8 cvt8(const float* p) {
    f32x4 a = *reinterpret_cast<const f32x4*>(p);
    f32x4 b = *reinterpret_cast<const f32x4*>(p + 4);
    bf16x8 r;
    r[0] = (__bf16)a[0]; r[1] = (__bf16)a[1]; r[2] = (__bf16)a[2]; r[3] = (__bf16)a[3];
    r[4] = (__bf16)b[0]; r[5] = (__bf16)b[1]; r[6] = (__bf16)b[2]; r[7] = (__bf16)b[3];
    return r;
}

// 16B coherent load/store (round-7/8-proven): sc0 sc1 -> device coherence point.
__device__ __forceinline__ void st16c(void* p, f32x4 v) {
    asm volatile("global_store_dwordx4 %0, %1, off sc0 sc1" :: "v"(p), "v"(v) : "memory");
}
__device__ __forceinline__ f32x4 ld16c(const void* p) {
    f32x4 r;
    asm volatile("global_load_dwordx4 %0, %1, off sc0 sc1" : "=v"(r) : "v"(p) : "memory");
    return r;
}
union cvu { f32x4 f; bf16x8 h8; __bf16 h[8]; };
union frg { f32x4 f; unsigned u[4]; bf16x8 h; };

// ---- mid-path (flags) helpers, round-11 proven ----
__device__ __forceinline__ void block_wait(const unsigned* slots, int nslots,
                                           unsigned target) {
    if (threadIdx.x < 64) {
        const int l = threadIdx.x;
        const int idx = l < nslots ? l : 0;
        for (;;) {
            unsigned v = __hip_atomic_load(&slots[idx * PADU], __ATOMIC_RELAXED,
                                           __HIP_MEMORY_SCOPE_AGENT);
            if (l >= nslots) v = target;
            if (__all((int)(v >= target))) break;
            __builtin_amdgcn_s_sleep(1);
        }
    }
    __syncthreads();
    asm volatile("" ::: "memory");
}
__device__ __forceinline__ unsigned minpoll(const unsigned* slots, int nslots) {
    const int l = threadIdx.x & 63;
    unsigned v = 0xFFFFFFFFu;
    if (l < nslots)
        v = __hip_atomic_load(&slots[l * PADU], __ATOMIC_RELAXED,
                              __HIP_MEMORY_SCOPE_AGENT);
    #pragma unroll
    for (int o = 32; o; o >>= 1) {
        unsigned u = (unsigned)__shfl_xor((int)v, o, 64);
        v = u < v ? u : v;
    }
    return v;
}
__device__ __forceinline__ void bsignal(unsigned* slot, unsigned val) {
    asm volatile("s_waitcnt vmcnt(0)" ::: "memory");
    __syncthreads();
    if (threadIdx.x == 0)
        __hip_atomic_store(slot, val, __ATOMIC_RELAXED, __HIP_MEMORY_SCOPE_AGENT);
}

// Fast tanh via v_exp; rel err ~1e-6 << bf16 storage quantization.
__device__ __forceinline__ float ftanh(float x) {
    float ax = fabsf(x);
    float e = __expf(-2.0f * ax);
    float r = (1.0f - e) / (1.0f + e);
    return x < 0.0f ? -r : r;
}

// Decode tokens to int32 (auto-detect int64 vs int32); optionally zero flags.
__global__ void tokens_kernel(const void* __restrict__ seq, int* __restrict__ tok,
                              unsigned* __restrict__ bar, int nbar) {
    int z = blockIdx.x * 256 + threadIdx.x;
    if (bar && z < nbar)
        __hip_atomic_store(&bar[z], 0u, __ATOMIC_RELAXED, __HIP_MEMORY_SCOPE_AGENT);
    const unsigned* u = (const unsigned*)seq;
    bool is64 = true;
    #pragma unroll 1
    for (int i = 0; i < 64; ++i) {
        if (u[2 * i + 1] != 0u) { is64 = false; break; }
    }
    int i = blockIdx.x * 256 + threadIdx.x;
    if (i < BB * SS) tok[i] = is64 ? (int)u[2 * i] : (int)u[i];
}

// fp32 [R][C] row-major -> bf16 [C][R]
__global__ __launch_bounds__(256) void transpose_kernel(
    const float* __restrict__ in, __bf16* __restrict__ out, int R, int C) {
    __shared__ float t[32][33];
    int bc = C >> 5;
    int br = blockIdx.x / bc;
    int bco = blockIdx.x % bc;
    int R0 = br << 5, C0 = bco << 5;
    int c = threadIdx.x & 31, r0 = threadIdx.x >> 5;
    #pragma unroll
    for (int i = 0; i < 4; ++i) {
        int r = r0 + i * 8;
        t[r][c] = in[(size_t)(R0 + r) * C + C0 + c];
    }
    __syncthreads();
    #pragma unroll
    for (int i = 0; i < 4; ++i) {
        int r = r0 + i * 8;
        out[(size_t)(C0 + r) * R + R0 + c] = (__bf16)t[c][r];
    }
}

// Zero big-ring slots 1..SS (data-validity markers: zero = not-yet-written).
__global__ void prezero_kernel(__bf16* __restrict__ h1R, __bf16* __restrict__ h2R) {
    const size_t n1 = (size_t)SS * BB * HH / 8;   // 16B units
    const size_t n2 = (size_t)SS * BB * EE / 8;
    u32x4 z = {0u, 0u, 0u, 0u};
    u32x4* p1 = (u32x4*)(h1R + (size_t)BB * HH);
    u32x4* p2 = (u32x4*)(h2R + (size_t)BB * EE);
    for (size_t i = (size_t)blockIdx.x * 256 + threadIdx.x; i < n1 + n2;
         i += (size_t)gridDim.x * 256) {
        if (i < n1) p1[i] = z; else p2[i - n1] = z;
    }
}

// Init slot 0 of rings (if given) + small parity buffers for fallback paths.
__global__ void init_kernel(const float* __restrict__ h1, const float* __restrict__ h2,
                            __bf16* __restrict__ r1, __bf16* __restrict__ r2,
                            __bf16* __restrict__ p1, __bf16* __restrict__ p2) {
    int i = blockIdx.x * 256 + threadIdx.x;
    if (i < BB * HH) {
        __bf16 v = (__bf16)h1[i];
        p1[i] = v;
        if (r1) r1[i] = v;
    }
    if (i < BB * EE) {
        __bf16 v = (__bf16)h2[i];
        p2[i] = v;
        if (r2) r2[i] = v;
    }
}

// ============ BIG-WS PATH: data-is-the-flag, zero-reuse rings ============
// h1 ring: SS+1 slots (slot t = h1_t); h2 ring: SS+1 slots. Slots 1..SS
// pre-zeroed each launch; bf16 state words are never 0x0000 in practice
// (only exact +0.0f; -0.0 encodes 0x8000). Consumers poll the DATA 16B
// fragments directly: valid when all 4 dwords != 0 (dword writes atomic).
// Producer: epilogue stores its tile (sc0 sc1) and proceeds — NO drain, NO
// flag, NO inter-block signal. Hop = ONE coherence-point leg instead of 4.
// If a dword is legitimately zero (prob ~0), the guard breaks and reads
// zeros — which ARE the correct values (only cost: a bounded stall).
// LDS reduce double-buffered [i&1]; one __syncthreads per step (safe: a wave
// passes poll@i+1 only after its own block's step-i epilogue is visible).
__global__ __launch_bounds__(256, 1) void rnn_persist7(
    const int* __restrict__ tok32, const float* __restrict__ embW,
    const float* __restrict__ b1, const float* __restrict__ b2,
    const __bf16* __restrict__ W1t, const __bf16* __restrict__ W2t,
    __bf16* __restrict__ h1r, __bf16* __restrict__ h2r,
    float* __restrict__ h1out, float* __restrict__ h2out) {
    const int bid = blockIdx.x;
    const bool g1 = bid < NWG1;
    const int rb = g1 ? bid : bid - NWG1;
    const int mi = rb & 3;
    const int ni = rb >> 2;
    const int m0 = mi << 4;
    const int n0 = ni << 6;
    const int tid = threadIdx.x;
    const int w = tid >> 6;
    const int l = tid & 63;
    const int l16 = l & 15;
    const int kg = l >> 4;

    __shared__ int tok_s[SS][16];
    __shared__ float red[2][4][16][68];

    if (g1) {
        for (int idx = tid; idx < SS * 16; idx += 256) {
            int t = idx >> 4, r = idx & 15;
            tok_s[t][r] = tok32[(m0 + r) * SS + t];
        }
    }

    // Register-resident weights: wave w holds K-slices {w+4t, t=0..11}.
    const __bf16* Wt = g1 ? W1t : W2t;
    bf16x8 wreg[12][4];
    #pragma unroll
    for (int t = 0; t < 12; ++t) {
        const int kb = 32 * (w + 4 * t) + kg * 8;
        #pragma unroll
        for (int nf = 0; nf < 4; ++nf)
            wreg[t][nf] = load_bf8(Wt + (size_t)(n0 + nf * 16 + l16) * KK + kb);
    }
    {   // Pin in the register file (round-3 lesson).
        f32x4* p1 = reinterpret_cast<f32x4*>(&wreg[0][0]);
        #pragma unroll
        for (int q = 0; q < 48; ++q) asm volatile("" : "+v"(p1[q]));
    }

    // Epilogue mapping (lanes<32): row = 4w + (l>>3), cols c1 = (l&7)*8.
    const int r1 = 4 * w + ((l & 31) >> 3);
    const int c1 = (l & 7) * 8;
    const float* bias = g1 ? b1 : b2;
    const f32x4 blo = *reinterpret_cast<const f32x4*>(bias + n0 + c1);
    const f32x4 bhi = *reinterpret_cast<const f32x4*>(bias + n0 + c1 + 4);

    __syncthreads();

    if (g1) {
        for (int i = 0; i < SS; ++i) {
            const __bf16* h1i = h1r + (size_t)i * (BB * HH);
            __bf16*       h1n = h1r + (size_t)(i + 1) * (BB * HH);

            // Pre-poll: embedding-part MFMAs (cached path).
            f32x4 acc[4] = {{0,0,0,0},{0,0,0,0},{0,0,0,0},{0,0,0,0}};
            const float* er = embW + (size_t)tok_s[i][l16] * EE;
            #pragma unroll
            for (int t = 0; t < 4; ++t) {
                bf16x8 ae = cvt8(er + 32 * (w + 4 * t) + kg * 8);
                #pragma unroll
                for (int nf = 0; nf < 4; ++nf)
                    acc[nf] = __builtin_amdgcn_mfma_f32_16x16x32_bf16(
                        ae, wreg[t][nf], acc[nf], 0, 0, 0);
            }
            __builtin_amdgcn_sched_barrier(0);

            // Data-validity poll: on pass, operands are already in registers.
            const __bf16* h1row = h1i + (m0 + l16) * HH;
            frg ff[8];
            int guard = 0;
            for (;;) {
                #pragma unroll
                for (int u = 0; u < 8; ++u)
                    ff[u].f = ld16c(h1row + 32 * (w + 4 * u) + kg * 8);
                asm volatile("s_waitcnt vmcnt(0)" ::: "memory");
                __builtin_amdgcn_sched_barrier(0);
                bool ok = true;
                #pragma unroll
                for (int u = 0; u < 8; ++u)
                    ok = ok && ff[u].u[0] && ff[u].u[1] && ff[u].u[2] && ff[u].u[3];
                if (__all(ok)) break;
                if (++guard > (1 << 16)) break;
                __builtin_amdgcn_s_sleep(4);
            }

            #pragma unroll
            for (int u = 0; u < 8; ++u)
                #pragma unroll
                for (int nf = 0; nf < 4; ++nf)
                    acc[nf] = __builtin_amdgcn_mfma_f32_16x16x32_bf16(
                        ff[u].h, wreg[u + 4][nf], acc[nf], 0, 0, 0);

            // D layout: col = lane&15, row = (lane>>4)*4 + reg.
            #pragma unroll
            for (int nf = 0; nf < 4; ++nf)
                #pragma unroll
                for (int q = 0; q < 4; ++q)
                    red[i & 1][w][kg * 4 + q][nf * 16 + l16] = acc[nf][q];
            __syncthreads();

            if ((l & 63) < 32) {
                f32x4 lo = blo, hi = bhi;
                #pragma unroll
                for (int p = 0; p < 4; ++p) {
                    lo += *reinterpret_cast<const f32x4*>(&red[i & 1][p][r1][c1]);
                    hi += *reinterpret_cast<const f32x4*>(&red[i & 1][p][r1][c1 + 4]);
                }
                cvu o;
                #pragma unroll
                for (int j = 0; j < 4; ++j) {
                    o.h[j]     = (__bf16)ftanh(lo[j]);
                    o.h[j + 4] = (__bf16)ftanh(hi[j]);
                }
                st16c(h1n + (m0 + r1) * HH + n0 + c1, o.f);
                if (i == SS - 1) {
                    float* op = h1out + (m0 + r1) * HH + n0 + c1;
                    #pragma unroll
                    for (int j = 0; j < 8; ++j)
                        op[j] = __bfloat162float(((__hip_bfloat16*)&o.h[j])[0]);
                }
            }
            // no drain, no signal — store-ack folds into next step's waits
        }
    } else {
        for (int j = 1; j <= SS; ++j) {
            const __bf16* h1j = h1r + (size_t)j * (BB * HH);
            const __bf16* h2p = h2r + (size_t)(j - 1) * (BB * EE);
            __bf16*       h2n = h2r + (size_t)j * (BB * EE);

            const __bf16* h1row = h1j + (m0 + l16) * HH;
            const __bf16* h2row = h2p + (m0 + l16) * EE;
            frg fa[8], fb[4];
            int guard = 0;
            for (;;) {
                #pragma unroll
                for (int u = 0; u < 8; ++u)
                    fa[u].f = ld16c(h1row + 32 * (w + 4 * u) + kg * 8);
                #pragma unroll
                for (int u = 0; u < 4; ++u)
                    fb[u].f = ld16c(h2row + 32 * (w + 4 * u) + kg * 8);
                asm volatile("s_waitcnt vmcnt(0)" ::: "memory");
                __builtin_amdgcn_sched_barrier(0);
                bool ok = true;
                #pragma unroll
                for (int u = 0; u < 8; ++u)
                    ok = ok && fa[u].u[0] && fa[u].u[1] && fa[u].u[2] && fa[u].u[3];
                #pragma unroll
                for (int u = 0; u < 4; ++u)
                    ok = ok && fb[u].u[0] && fb[u].u[1] && fb[u].u[2] && fb[u].u[3];
                if (__all(ok)) break;
                if (++guard > (1 << 16)) break;
                __builtin_amdgcn_s_sleep(4);
            }

            f32x4 acc[4] = {{0,0,0,0},{0,0,0,0},{0,0,0,0},{0,0,0,0}};
            #pragma unroll
            for (int t = 0; t < 8; ++t)
                #pragma unroll
                for (int nf = 0; nf < 4; ++nf)
                    acc[nf] = __builtin_amdgcn_mfma_f32_16x16x32_bf16(
                        fa[t].h, wreg[t][nf], acc[nf], 0, 0, 0);
            #pragma unroll
            for (int u = 0; u < 4; ++u)
                #pragma unroll
                for (int nf = 0; nf < 4; ++nf)
                    acc[nf] = __builtin_amdgcn_mfma_f32_16x16x32_bf16(
                        fb[u].h, wreg[u + 8][nf], acc[nf], 0, 0, 0);

            #pragma unroll
            for (int nf = 0; nf < 4; ++nf)
                #pragma unroll
                for (int q = 0; q < 4; ++q)
                    red[j & 1][w][kg * 4 + q][nf * 16 + l16] = acc[nf][q];
            __syncthreads();

            if ((l & 63) < 32) {
                f32x4 lo = blo, hi = bhi;
                #pragma unroll
                for (int p = 0; p < 4; ++p) {
                    lo += *reinterpret_cast<const f32x4*>(&red[j & 1][p][r1][c1]);
                    hi += *reinterpret_cast<const f32x4*>(&red[j & 1][p][r1][c1 + 4]);
                }
                cvu o;
                #pragma unroll
                for (int q = 0; q < 4; ++q) {
                    o.h[q]     = (__bf16)ftanh(lo[q]);
                    o.h[q + 4] = (__bf16)ftanh(hi[q]);
                }
                st16c(h2n + (m0 + r1) * EE + n0 + c1, o.f);
                if (j == SS) {
                    float* op = h2out + (m0 + r1) * EE + n0 + c1;
                    #pragma unroll
                    for (int q = 0; q < 8; ++q)
                        op[q] = __bfloat162float(((__hip_bfloat16*)&o.h[q])[0]);
                }
            }
        }
    }
}

// ============ MID-WS PATH: round-11 proven flags+ring kernel ============
__global__ __launch_bounds__(256, 1) void rnn_persist6(
    const int* __restrict__ tok32, const float* __restrict__ embW,
    const float* __restrict__ b1, const float* __restrict__ b2,
    const __bf16* __restrict__ W1t, const __bf16* __restrict__ W2t,
    __bf16* __restrict__ h1r, __bf16* __restrict__ h2r,
    float* __restrict__ h1out, float* __restrict__ h2out,
    unsigned* __restrict__ bar) {
    const int bid = blockIdx.x;
    const bool g1 = bid < NWG1;
    const int rb = g1 ? bid : bid - NWG1;
    const int mi = rb & 3;
    const int ni = rb >> 2;
    const int m0 = mi << 4;
    const int n0 = ni << 6;
    const int tid = threadIdx.x;
    const int w = tid >> 6;
    const int l = tid & 63;
    const int l16 = l & 15;
    const int kg = l >> 4;
    unsigned* f1s = bar + mi * (32 * PADU);
    unsigned* f2s = f1s + 16 * PADU;
    unsigned* myf = g1 ? &f1s[ni * PADU] : &f2s[ni * PADU];

    __shared__ int tok_s[SS][16];
    __shared__ float red[2][4][16][68];

    if (g1) {
        for (int idx = tid; idx < SS * 16; idx += 256) {
            int t = idx >> 4, r = idx & 15;
            tok_s[t][r] = tok32[(m0 + r) * SS + t];
        }
    }

    const __bf16* Wt = g1 ? W1t : W2t;
    bf16x8 wreg[12][4];
    #pragma unroll
    for (int t = 0; t < 12; ++t) {
        const int kb = 32 * (w + 4 * t) + kg * 8;
        #pragma unroll
        for (int nf = 0; nf < 4; ++nf)
            wreg[t][nf] = load_bf8(Wt + (size_t)(n0 + nf * 16 + l16) * KK + kb);
    }
    {
        f32x4* p1 = reinterpret_cast<f32x4*>(&wreg[0][0]);
        #pragma unroll
        for (int q = 0; q < 48; ++q) asm volatile("" : "+v"(p1[q]));
    }

    const int r1 = 4 * w + ((l & 31) >> 3);
    const int c1 = (l & 7) * 8;
    const float* bias = g1 ? b1 : b2;
    const f32x4 blo = *reinterpret_cast<const f32x4*>(bias + n0 + c1);
    const f32x4 bhi = *reinterpret_cast<const f32x4*>(bias + n0 + c1 + 4);

    unsigned f2c = 0;
    __syncthreads();

    if (g1) {
        for (int i = 0; i < SS; ++i) {
            const __bf16* h1i = h1r + (size_t)(i & (RINGM - 1)) * BB * HH;
            __bf16*       h1n = h1r + (size_t)((i + 1) & (RINGM - 1)) * BB * HH;

            f32x4 acc[4] = {{0,0,0,0},{0,0,0,0},{0,0,0,0},{0,0,0,0}};
            const float* er = embW + (size_t)tok_s[i][l16] * EE;
            #pragma unroll
            for (int t = 0; t < 4; ++t) {
                bf16x8 ae = cvt8(er + 32 * (w + 4 * t) + kg * 8);
                #pragma unroll
                for (int nf = 0; nf < 4; ++nf)
                    acc[nf] = __builtin_amdgcn_mfma_f32_16x16x32_bf16(
                        ae, wreg[t][nf], acc[nf], 0, 0, 0);
            }
            __builtin_amdgcn_sched_barrier(0);

            if (i >= RINGM - 1 && (int)f2c < i - (RINGM - 1)) {
                do { f2c = minpoll(f2s, 8); } while ((int)f2c < i - (RINGM - 1));
            }

            if (i) block_wait(f1s, 16, (unsigned)i);

            const __bf16* h1row = h1i + (m0 + l16) * HH;
            bf16x8 ah[8];
            #pragma unroll
            for (int u = 0; u < 8; ++u) {
                cvu t_; t_.f = ld16c(h1row + 32 * (w + 4 * u) + kg * 8);
                ah[u] = t_.h8;
            }
            asm volatile("s_waitcnt vmcnt(0)" ::: "memory");
            __builtin_amdgcn_sched_barrier(0);

            #pragma unroll
            for (int u = 0; u < 8; ++u)
                #pragma unroll
                for (int nf = 0; nf < 4; ++nf)
                    acc[nf] = __builtin_amdgcn_mfma_f32_16x16x32_bf16(
                        ah[u], wreg[u + 4][nf], acc[nf], 0, 0, 0);

            #pragma unroll
            for (int nf = 0; nf < 4; ++nf)
                #pragma unroll
                for (int q = 0; q < 4; ++q)
                    red[i & 1][w][kg * 4 + q][nf * 16 + l16] = acc[nf][q];
            __syncthreads();

            if ((l & 63) < 32) {
                f32x4 lo = blo, hi = bhi;
                #pragma unroll
                for (int p = 0; p < 4; ++p) {
                    lo += *reinterpret_cast<const f32x4*>(&red[i & 1][p][r1][c1]);
                    hi += *reinterpret_cast<const f32x4*>(&red[i & 1][p][r1][c1 + 4]);
                }
                cvu o;
                #pragma unroll
                for (int j = 0; j < 4; ++j) {
                    o.h[j]     = (__bf16)ftanh(lo[j]);
                    o.h[j + 4] = (__bf16)ftanh(hi[j]);
                }
                st16c(h1n + (m0 + r1) * HH + n0 + c1, o.f);
                if (i == SS - 1) {
                    float* op = h1out + (m0 + r1) * HH + n0 + c1;
                    #pragma unroll
                    for (int j = 0; j < 8; ++j)
                        op[j] = __bfloat162float(((__hip_bfloat16*)&o.h[j])[0]);
                }
            }
            bsignal(myf, (unsigned)(i + 1));
        }
    } else {
        for (int j = 1; j <= SS; ++j) {
            const __bf16* h1j = h1r + (size_t)(j & (RINGM - 1)) * BB * HH;
            const __bf16* h2p = h2r + (size_t)((j - 1) & (RINGM - 1)) * BB * EE;
            __bf16*       h2n = h2r + (size_t)(j & (RINGM - 1)) * BB * EE;

            block_wait(f1s, 16, (unsigned)j);
            const __bf16* h1row = h1j + (m0 + l16) * HH;
            bf16x8 ah[8];
            #pragma unroll
            for (int t = 0; t < 8; ++t) {
                cvu t_; t_.f = ld16c(h1row + 32 * (w + 4 * t) + kg * 8);
                ah[t] = t_.h8;
            }
            if (j >= 2) block_wait(f2s, 8, (unsigned)(j - 1));
            const __bf16* h2row = h2p + (m0 + l16) * EE;
            bf16x8 a2[4];
            #pragma unroll
            for (int u = 0; u < 4; ++u) {
                cvu t_; t_.f = ld16c(h2row + 32 * (w + 4 * u) + kg * 8);
                a2[u] = t_.h8;
            }
            asm volatile("s_waitcnt vmcnt(0)" ::: "memory");
            __builtin_amdgcn_sched_barrier(0);

            f32x4 acc[4] = {{0,0,0,0},{0,0,0,0},{0,0,0,0},{0,0,0,0}};
            #pragma unroll
            for (int t = 0; t < 8; ++t)
                #pragma unroll
                for (int nf = 0; nf < 4; ++nf)
                    acc[nf] = __builtin_amdgcn_mfma_f32_16x16x32_bf16(
                        ah[t], wreg[t][nf], acc[nf], 0, 0, 0);
            #pragma unroll
            for (int u = 0; u < 4; ++u)
                #pragma unroll
                for (int nf = 0; nf < 4; ++nf)
                    acc[nf] = __builtin_amdgcn_mfma_f32_16x16x32_bf16(
                        a2[u], wreg[u + 8][nf], acc[nf], 0, 0, 0);

            #pragma unroll
            for (int nf = 0; nf < 4; ++nf)
                #pragma unroll
                for (int q = 0; q < 4; ++q)
                    red[j & 1][w][kg * 4 + q][nf * 16 + l16] = acc[nf][q];
            __syncthreads();

            if ((l & 63) < 32) {
                f32x4 lo = blo, hi = bhi;
                #pragma unroll
                for (int p = 0; p < 4; ++p) {
                    lo += *reinterpret_cast<const f32x4*>(&red[j & 1][p][r1][c1]);
                    hi += *reinterpret_cast<const f32x4*>(&red[j & 1][p][r1][c1 + 4]);
                }
                cvu o;
                #pragma unroll
                for (int q = 0; q < 4; ++q) {
                    o.h[q]     = (__bf16)ftanh(lo[q]);
                    o.h[q + 4] = (__bf16)ftanh(hi[q]);
                }
                st16c(h2n + (m0 + r1) * EE + n0 + c1, o.f);
                if (j == SS) {
                    float* op = h2out + (m0 + r1) * EE + n0 + c1;
                    #pragma unroll
                    for (int q = 0; q < 8; ++q)
                        op[q] = __bfloat162float(((__hip_bfloat16*)&o.h[q])[0]);
                }
            }
            bsignal(myf, (unsigned)j);
        }
    }
}

// Fallback per-step kernel (round-1 proven path).
__global__ __launch_bounds__(256) void step_kernel(
    const int* __restrict__ tok32,
    const float* __restrict__ embW,
    const float* __restrict__ b1, const float* __restrict__ b2,
    const __bf16* __restrict__ W1t, const __bf16* __restrict__ W2t,
    const __bf16* __restrict__ h1cur, __bf16* __restrict__ h1next,
    const __bf16* __restrict__ h2cur, __bf16* __restrict__ h2next,
    float* __restrict__ h1f32, float* __restrict__ h2f32,
    int t, int g1, int g2) {
    const int bid = blockIdx.x;
    const bool is1 = bid < 128;
    if (is1 ? (g1 == 0) : (g2 == 0)) return;
    const int rb = is1 ? bid : (bid - 128);
    const int mi = rb & 3;
    const int ni = rb >> 2;
    const int m0 = mi << 4;
    const int n0 = ni << 5;
    const int N = is1 ? HH : EE;
    const int tid = threadIdx.x;
    const int w = tid >> 6;
    const int l = tid & 63;
    const int l16 = l & 15;
    const int kg = l >> 4;

    __shared__ int tok_s[16];
    __shared__ float red[4][16][33];

    if (is1 && tid < 16) tok_s[tid] = tok32[(m0 + tid) * SS + t];
    __syncthreads();

    const __bf16* Wt = is1 ? W1t : W2t;
    f32x4 acc0 = {0.f, 0.f, 0.f, 0.f};
    f32x4 acc1 = {0.f, 0.f, 0.f, 0.f};
    const int row = m0 + l16;
    const int kb = w * 384;

    #pragma unroll 4
    for (int kk = 0; kk < 384; kk += 32) {
        const int k = kb + kk + kg * 8;
        bf16x8 a;
        if (is1) {
            if (k < EE) a = cvt8(embW + (size_t)tok_s[l16] * EE + k);
            else        a = load_bf8(h1cur + row * HH + (k - EE));
        } else {
            if (k < HH) a = load_bf8(h1cur + row * HH + k);
            else        a = load_bf8(h2cur + row * EE + (k - HH));
        }
        bf16x8 bf0 = load_bf8(Wt + (size_t)(n0 + l16) * KK + k);
        bf16x8 bf1 = load_bf8(Wt + (size_t)(n0 + 16 + l16) * KK + k);
        acc0 = __builtin_amdgcn_mfma_f32_16x16x32_bf16(a, bf0, acc0, 0, 0, 0);
        acc1 = __builtin_amdgcn_mfma_f32_16x16x32_bf16(a, bf1, acc1, 0, 0, 0);
    }

    #pragma unroll
    for (int i = 0; i < 4; ++i) {
        red[w][kg * 4 + i][l16]      = acc0[i];
        red[w][kg * 4 + i][16 + l16] = acc1[i];
    }
    __syncthreads();

    const float* bias = is1 ? b1 : b2;
    for (int c = tid; c < 512; c += 256) {
        int m = c >> 5, n = c & 31;
        float s = red[0][m][n] + red[1][m][n] + red[2][m][n] + red[3][m][n];
        s = tanhf(s + bias[n0 + n]);
        int gi = (m0 + m) * N + (n0 + n);
        if (is1) {
            h1next[gi] = (__bf16)s;
            if (h1f32) h1f32[gi] = s;
        } else {
            h2next[gi] = (__bf16)s;
            if (h2f32) h2f32[gi] = s;
        }
    }
}

// out[64, V] = h2 @ emb_W^T + out_b; h2 read as fp32 from h2out region.
__global__ __launch_bounds__(256) void proj_kernel(
    const float* __restrict__ h2f,
    const float* __restrict__ embW,
    const float* __restrict__ outb,
    float* __restrict__ out) {
    const int v0 = blockIdx.x << 6;
    const int tid = threadIdx.x;
    const int w = tid >> 6;
    const int l = tid & 63;
    const int l16 = l & 15, kg = l >> 4;
    const int vcol = v0 + w * 16 + l16;
    const int vr = vcol < VV ? vcol : VV - 1;
    f32x4 acc[4] = {{0,0,0,0},{0,0,0,0},{0,0,0,0},{0,0,0,0}};
    #pragma unroll 2
    for (int k0 = 0; k0 < EE; k0 += 32) {
        const int k = k0 + kg * 8;
        bf16x8 bfr = cvt8(embW + (size_t)vr * EE + k);
        #pragma unroll
        for (int mf = 0; mf < 4; ++mf) {
            bf16x8 a = cvt8(h2f + (size_t)(mf * 16 + l16) * EE + k);
            acc[mf] = __builtin_amdgcn_mfma_f32_16x16x32_bf16(a, bfr, acc[mf], 0, 0, 0);
        }
    }
    if (vcol < VV) {
        const float bb = outb[vcol];
        #pragma unroll
        for (int mf = 0; mf < 4; ++mf) {
            #pragma unroll
            for (int i = 0; i < 4; ++i) {
                int b = mf * 16 + kg * 4 + i;
                out[(size_t)b * VV + vcol] = acc[mf][i] + bb;
            }
        }
    }
}

extern "C" void kernel_launch(void* const* d_in, const int* in_sizes, int n_in,
                              void* d_out, int out_size, void* d_ws, size_t ws_size,
                              hipStream_t stream) {
    const void* seq      = d_in[0];
    const float* init_h1 = (const float*)d_in[1];
    const float* init_h2 = (const float*)d_in[2];
    const float* embW    = (const float*)d_in[3];
    const float* W1      = (const float*)d_in[4];
    const float* b1      = (const float*)d_in[5];
    const float* W2      = (const float*)d_in[6];
    const float* b2      = (const float*)d_in[7];
    const float* outb    = (const float*)d_in[8];
    float* out = (float*)d_out;

    char* ws = (char*)d_ws;
    int* tok = (int*)ws;                 ws += (size_t)BB * SS * 4;
    __bf16* W1t = (__bf16*)ws;           ws += (size_t)HH * KK * 2;
    __bf16* W2t = (__bf16*)ws;           ws += (size_t)EE * KK * 2;
    __bf16* h1p = (__bf16*)ws;           ws += (size_t)2 * BB * HH * 2;
    __bf16* h2p = (__bf16*)ws;           ws += (size_t)2 * BB * EE * 2;
    unsigned* bar = (unsigned*)ws;       ws += (size_t)4 * 32 * PADU * 4;
    char* rings = ws;
    size_t base = (size_t)(rings - (char*)d_ws);
    size_t needBig = base + (size_t)(SS + 1) * BB * HH * 2 + (size_t)(SS + 1) * BB * EE * 2;
    size_t needMid = base + (size_t)RINGM * BB * HH * 2 + (size_t)RINGM * BB * EE * 2;
    __bf16* h1Rb = (__bf16*)rings;
    __bf16* h2Rb = (__bf16*)(rings + (size_t)(SS + 1) * BB * HH * 2);
    __bf16* h1Rm = (__bf16*)rings;
    __bf16* h2Rm = (__bf16*)(rings + (size_t)RINGM * BB * HH * 2);

    float* h1out = out + (size_t)BB * VV;
    float* h2out = h1out + (size_t)BB * HH;

    const bool big = ws_size >= needBig;
    const bool mid = !big && ws_size >= needMid;

    hipLaunchKernelGGL(tokens_kernel, dim3(128), dim3(256), 0, stream,
                       seq, tok, mid ? bar : (unsigned*)nullptr, 4 * 32 * PADU);
    hipLaunchKernelGGL(transpose_kernel, dim3((KK / 32) * (HH / 32)), dim3(256), 0, stream,
                       W1, W1t, KK, HH);
    hipLaunchKernelGGL(transpose_kernel, dim3((KK / 32) * (EE / 32)), dim3(256), 0, stream,
                       W2, W2t, KK, EE);

    const int* tok_c = tok;
    const __bf16* W1t_c = W1t;
    const __bf16* W2t_c = W2t;
    bool done = false;

    if (big) {
        hipLaunchKernelGGL(prezero_kernel, dim3(1024), dim3(256), 0, stream, h1Rb, h2Rb);
        hipLaunchKernelGGL(init_kernel, dim3(256), dim3(256), 0, stream,
                           init_h1, init_h2, h1Rb, h2Rb, h1p, h2p);
        void* args[] = {
            (void*)&tok_c, (void*)&embW, (void*)&b1, (void*)&b2,
            (void*)&W1t_c, (void*)&W2t_c,
            (void*)&h1Rb, (void*)&h2Rb, (void*)&h1out, (void*)&h2out
        };
        done = hipLaunchCooperativeKernel((void*)rnn_persist7, dim3(NWG), dim3(256),
                                          args, 0, stream) == hipSuccess;
    } else if (mid) {
        hipLaunchKernelGGL(init_kernel, dim3(256), dim3(256), 0, stream,
                           init_h1, init_h2, h1Rm, h2Rm, h1p, h2p);
        void* args[] = {
            (void*)&tok_c, (void*)&embW, (void*)&b1, (void*)&b2,
            (void*)&W1t_c, (void*)&W2t_c,
            (void*)&h1Rm, (void*)&h2Rm, (void*)&h1out, (void*)&h2out, (void*)&bar
        };
        done = hipLaunchCooperativeKernel((void*)rnn_persist6, dim3(NWG), dim3(256),
                                          args, 0, stream) == hipSuccess;
    } else {
        hipLaunchKernelGGL(init_kernel, dim3(256), dim3(256), 0, stream,
                           init_h1, init_h2, (__bf16*)nullptr, (__bf16*)nullptr, h1p, h2p);
    }

    if (!done) {
        // Deterministic fallback: proven per-step path (round 1).
        __bf16* h1bf[2] = {h1p, h1p + (size_t)BB * HH};
        __bf16* h2bf[2] = {h2p, h2p + (size_t)BB * EE};
        for (int t = 0; t <= SS; ++t) {
            int g1 = (t < SS) ? 1 : 0;
            int g2 = (t >= 1) ? 1 : 0;
            const __bf16* h1cur = h1bf[t & 1];
            __bf16* h1next      = h1bf[(t + 1) & 1];
            const __bf16* h2cur = h2bf[(t + 1) & 1];
            __bf16* h2next      = h2bf[t & 1];
            float* h1f = (t == SS - 1) ? h1out : nullptr;
            float* h2f = (t == SS) ? h2out : nullptr;
            hipLaunchKernelGGL(step_kernel, dim3(192), dim3(256), 0, stream,
                               tok, embW, b1, b2, W1t, W2t,
                               h1cur, h1next, h2cur, h2next, h1f, h2f, t, g1, g2);
        }
    }

    // All paths leave the final h2 (fp32) in h2out.
    hipLaunchKernelGGL(proj_kernel, dim3((VV + 63) / 64), dim3(256), 0, stream,
                       h2out, embW, outb, out);
}